// Round 2
// baseline (940.077 us; speedup 1.0000x reference)
//
#include <hip/hip_runtime.h>

#define NUM_VOXELS     1000000
#define N_POINTS       1500000
#define TOTAL_PROP_PTS 1000000
#define NUM_PROPOSALS  2048
#define IN_CH          134
#define M_OUT          16

typedef unsigned int  uint;
typedef unsigned short ushort;

// round-to-nearest-even f32 -> bf16
__device__ __forceinline__ ushort f2bf(float f) {
    uint u = __float_as_uint(f);
    uint r = (u + 0x7FFFu + ((u >> 16) & 1u)) >> 16;
    return (ushort)r;
}

// ---------------------------------------------------------------------------
// K0a: zero the per-voxel referenced flags (1 MB). Kernel instead of
// hipMemsetAsync to stay safely inside graph-capture rules.
// ---------------------------------------------------------------------------
__global__ void k_zero_flags(uint* __restrict__ flags4) {
    int i = blockIdx.x * 256 + threadIdx.x;
    if (i < NUM_VOXELS / 4) flags4[i] = 0;
}

// ---------------------------------------------------------------------------
// K0b: flag[v] = 1 for every voxel actually gathered by the proposal pass.
// Plain stores (all write 1) -- no atomics needed.
// ---------------------------------------------------------------------------
__global__ void k_set_flags(const int* __restrict__ prop_idx,
                            const int* __restrict__ p2v,
                            unsigned char* __restrict__ flags) {
    int t = blockIdx.x * 256 + threadIdx.x;
    if (t < TOTAL_PROP_PTS) {
        int p = prop_idx[2 * t + 1];
        flags[p2v[p]] = 1;
    }
}

// ---------------------------------------------------------------------------
// K1: feats_bf16 = relu(voxel_feats @ W), computed ONLY for flagged voxels
// (~52% referenced => ~48% of the 536 MB A-read skipped via exec-masked
// loads; half-wave-per-row staging keeps skips at full-256B granularity).
// Wave-private LDS chunk [64 rows][65 cols] (bank-free), W via wave-uniform
// scalar loads. Output packed bf16 (32 B/voxel) -> K2's gather set fits L2/L3.
// ---------------------------------------------------------------------------
__global__ __launch_bounds__(256, 2) void k_gemm_relu(
    const float* __restrict__ A, const float* __restrict__ W,
    const unsigned char* __restrict__ flags,
    uint* __restrict__ featsb)          // [NUM_VOXELS][8] uints = 16 bf16
{
    __shared__ float lds[4][64 * 65];
    const int wave = threadIdx.x >> 6;
    const int lane = threadIdx.x & 63;
    const int v0   = blockIdx.x * 256 + wave * 64;
    if (v0 >= NUM_VOXELS) return;       // NUM_VOXELS % 64 == 0

    const int myflag = flags[v0 + lane];   // coalesced 64 B per wave

    float* chunk = lds[wave];
    float acc[M_OUT];
#pragma unroll
    for (int c = 0; c < M_OUT; ++c) acc[c] = 0.f;

    for (int kc = 0; kc < IN_CH; kc += 64) {
        const int KC = (IN_CH - kc) >= 64 ? 64 : (IN_CH - kc);
        if (KC == 64) {
            const int half = lane >> 5;
            const int c2   = (lane & 31) * 2;
#pragma unroll 8
            for (int j = 0; j < 32; ++j) {
                const int row = j * 2 + half;
                const int rf  = __shfl(myflag, row, 64);  // row flag, half-wave uniform
                if (rf) {
                    const float2 val = *(const float2*)(A + (size_t)(v0 + row) * IN_CH + kc + c2);
                    chunk[row * 65 + c2]     = val.x;
                    chunk[row * 65 + c2 + 1] = val.y;
                }
            }
        } else {
            // tail KC = 6: 64*6 = 384 elements
#pragma unroll
            for (int j = 0; j < 6; ++j) {
                const int e   = j * 64 + lane;
                const int row = e / 6;
                const int col = e - row * 6;
                const int rf  = __shfl(myflag, row, 64);
                if (rf) chunk[row * 65 + col] = A[(size_t)(v0 + row) * IN_CH + kc + col];
            }
        }
        // compute for all 64 rows (garbage in unflagged rows is discarded)
        const float* wbase = W + kc * M_OUT;
        for (int kk = 0; kk < KC; ++kk) {
            const float a = chunk[lane * 65 + kk];
            const float* wr = wbase + kk * M_OUT;
#pragma unroll
            for (int c = 0; c < M_OUT; ++c) acc[c] = fmaf(a, wr[c], acc[c]);
        }
    }

    if (myflag) {
        uint u[8];
#pragma unroll
        for (int i = 0; i < 8; ++i) {
            const float lo = fmaxf(acc[2 * i],     0.f);
            const float hi = fmaxf(acc[2 * i + 1], 0.f);
            u[i] = (uint)f2bf(lo) | ((uint)f2bf(hi) << 16);
        }
        uint4* orow = (uint4*)(featsb + (size_t)(v0 + lane) * 8);
        orow[0] = make_uint4(u[0], u[1], u[2], u[3]);
        orow[1] = make_uint4(u[4], u[5], u[6], u[7]);
    }
}

// ---------------------------------------------------------------------------
// K2: per-proposal segmented mean (bf16 gathers, f32 accumulate) + batchId +
// objectness. One block per contiguous segment; thread-per-point keeps 256
// independent idx->p2v->feats chains in flight; shfl+LDS reduction.
// out layout (f32): [P*16 means][P batchId][P ones]
// ---------------------------------------------------------------------------
__global__ __launch_bounds__(256) void k_propmean(
    const uint*  __restrict__ featsb,
    const int*   __restrict__ p2v,
    const int*   __restrict__ prop_idx,
    const int*   __restrict__ offsets,
    const int*   __restrict__ locs,
    float*       __restrict__ out)
{
    const int s   = blockIdx.x;
    const int tid = threadIdx.x;
    const int t0  = offsets[s];
    const int t1  = offsets[s + 1];

    float acc[M_OUT];
#pragma unroll
    for (int c = 0; c < M_OUT; ++c) acc[c] = 0.f;

    for (int t = t0 + tid; t < t1; t += 256) {
        const int p = prop_idx[2 * t + 1];
        const int v = p2v[p];
        const uint4* fp = (const uint4*)(featsb + (size_t)v * 8);
        const uint4 q0 = fp[0], q1 = fp[1];
        const uint u[8] = {q0.x, q0.y, q0.z, q0.w, q1.x, q1.y, q1.z, q1.w};
#pragma unroll
        for (int i = 0; i < 8; ++i) {
            acc[2 * i]     += __uint_as_float(u[i] << 16);
            acc[2 * i + 1] += __uint_as_float(u[i] & 0xFFFF0000u);
        }
    }

#pragma unroll
    for (int c = 0; c < M_OUT; ++c) {
#pragma unroll
        for (int off = 32; off > 0; off >>= 1)
            acc[c] += __shfl_down(acc[c], off, 64);
    }

    __shared__ float red[4][M_OUT];
    const int lane = tid & 63, wv = tid >> 6;
    if (lane == 0) {
#pragma unroll
        for (int c = 0; c < M_OUT; ++c) red[wv][c] = acc[c];
    }
    __syncthreads();

    if (tid < M_OUT) {
        const float sum = red[0][tid] + red[1][tid] + red[2][tid] + red[3][tid];
        const float cnt = (float)(t1 - t0);
        out[s * M_OUT + tid] = sum / fmaxf(cnt, 1.f);
    }
    if (tid == 0) {
        const int p = prop_idx[2 * t0 + 1];
        out[NUM_PROPOSALS * M_OUT + s]                 = (float)locs[4 * p];
        out[NUM_PROPOSALS * M_OUT + NUM_PROPOSALS + s] = 1.0f;
    }
}

// ---------------------------------------------------------------------------
extern "C" void kernel_launch(void* const* d_in, const int* in_sizes, int n_in,
                              void* d_out, int out_size, void* d_ws, size_t ws_size,
                              hipStream_t stream)
{
    const float* A    = (const float*)d_in[0];   // voxel_feats [1M][134]
    const float* W    = (const float*)d_in[1];   // [134][16]
    const int*   p2v  = (const int*)  d_in[2];   // [1.5M]
    const int*   pidx = (const int*)  d_in[3];   // [1M][2]
    const int*   offs = (const int*)  d_in[4];   // [2049]
    const int*   locs = (const int*)  d_in[5];   // [1.5M][4]
    float*       out  = (float*)      d_out;     // 36864 f32

    // ws layout: [0, 32MB) bf16 feats (1M voxels x 8 uints), then 1MB flags
    uint*          featsb = (uint*)d_ws;
    unsigned char* flags  = (unsigned char*)d_ws + (size_t)NUM_VOXELS * 32;

    k_zero_flags<<<(NUM_VOXELS / 4 + 255) / 256, 256, 0, stream>>>((uint*)flags);
    k_set_flags<<<(TOTAL_PROP_PTS + 255) / 256, 256, 0, stream>>>(pidx, p2v, flags);
    k_gemm_relu<<<(NUM_VOXELS + 255) / 256, 256, 0, stream>>>(A, W, flags, featsb);
    k_propmean<<<NUM_PROPOSALS, 256, 0, stream>>>(featsb, p2v, pidx, offs, locs, out);
}

// Round 3
// 931.250 us; speedup vs baseline: 1.0095x; 1.0095x over previous
//
#include <hip/hip_runtime.h>

#define NUM_VOXELS     1000000
#define N_POINTS       1500000
#define TOTAL_PROP_PTS 1000000
#define NUM_PROPOSALS  2048
#define IN_CH          134
#define M_OUT          16

typedef unsigned int   uint;
typedef unsigned short ushort;

// round-to-nearest-even f32 -> bf16
__device__ __forceinline__ ushort f2bf(float f) {
    uint u = __float_as_uint(f);
    uint r = (u + 0x7FFFu + ((u >> 16) & 1u)) >> 16;
    return (ushort)r;
}

// ---------------------------------------------------------------------------
// K0: zero per-voxel flags (1 MB) + the compaction counter.
// ---------------------------------------------------------------------------
__global__ void k_zero(uint* __restrict__ flags4, int* __restrict__ count) {
    int i = blockIdx.x * 256 + threadIdx.x;
    if (i < NUM_VOXELS / 4) flags4[i] = 0;
    if (i == 0) *count = 0;
}

// ---------------------------------------------------------------------------
// K0b: flag[v] = 1 for every voxel gathered by the proposal pass.
// Plain byte stores (all write 1) -- no atomics needed.
// ---------------------------------------------------------------------------
__global__ void k_set_flags(const int* __restrict__ prop_idx,
                            const int* __restrict__ p2v,
                            unsigned char* __restrict__ flags) {
    int t = blockIdx.x * 256 + threadIdx.x;
    if (t < TOTAL_PROP_PTS) {
        int p = prop_idx[2 * t + 1];
        flags[p2v[p]] = 1;
    }
}

// ---------------------------------------------------------------------------
// K0c: compact flagged voxel ids into a dense worklist (order irrelevant;
// per-wave ballot + one atomicAdd per wave keeps ids ascending within a wave
// -> good row locality in K1).
// ---------------------------------------------------------------------------
__global__ __launch_bounds__(256) void k_compact(
    const unsigned char* __restrict__ flags,
    int* __restrict__ ids, int* __restrict__ count)
{
    const int i    = blockIdx.x * 256 + threadIdx.x;
    const int lane = threadIdx.x & 63;
    const int f    = (i < NUM_VOXELS) ? (int)flags[i] : 0;
    const unsigned long long m = __ballot(f);
    const int cnt = __popcll(m);
    int base = 0;
    if (lane == 0 && cnt) base = atomicAdd(count, cnt);
    base = __shfl(base, 0, 64);
    if (f) {
        const unsigned long long lt = m & ((1ull << lane) - 1ull);
        ids[base + __popcll(lt)] = i;
    }
}

// ---------------------------------------------------------------------------
// K1: feats_bf16 = relu(voxel_feats @ W) over the COMPACT worklist only.
// One LANE per voxel: the lane streams its own 536 B row as float2 bursts of
// 8 (consecutive same-cache-line loads -> MSHR-merged, MLP=8), FMAs directly
// from registers against wave-uniform W (scalar s_loads). No LDS, no shfl,
// no branches in the hot loop; all loop bounds compile-time -> full unroll.
// LDS=0 + ~50 VGPR -> 16 waves/CU to hide latency.
// ---------------------------------------------------------------------------
__global__ __launch_bounds__(256, 4) void k_gemm_relu(
    const float* __restrict__ A, const float* __restrict__ W,
    const int* __restrict__ ids, const int* __restrict__ count,
    uint* __restrict__ featsb)          // [NUM_VOXELS][8] uints = 16 bf16
{
    const int cnt = *count;
    const int idx = blockIdx.x * 256 + threadIdx.x;
    if ((idx & ~63) >= cnt) return;     // whole wave past the worklist
    const int  slot = (idx < cnt) ? idx : (cnt - 1);   // dup-last for tail lanes
    const int  vid  = ids[slot];
    const float2* __restrict__ row = (const float2*)(A + (size_t)vid * IN_CH);

    float acc[M_OUT];
#pragma unroll
    for (int c = 0; c < M_OUT; ++c) acc[c] = 0.f;

    // k = 0..127 in 8 chunks of 16; loads batched 8-deep per chunk.
    for (int ch = 0; ch < 8; ++ch) {
        float2 b[8];
#pragma unroll
        for (int j = 0; j < 8; ++j) b[j] = row[ch * 8 + j];
        const float* __restrict__ wb = W + ch * 16 * M_OUT;
#pragma unroll
        for (int j = 0; j < 8; ++j) {
#pragma unroll
            for (int c = 0; c < M_OUT; ++c) {
                acc[c] = fmaf(b[j].x, wb[(2 * j)     * M_OUT + c], acc[c]);
                acc[c] = fmaf(b[j].y, wb[(2 * j + 1) * M_OUT + c], acc[c]);
            }
        }
    }
    // tail k = 128..133
    {
        float2 t0 = row[64], t1 = row[65], t2 = row[66];
        const float a[6] = {t0.x, t0.y, t1.x, t1.y, t2.x, t2.y};
        const float* __restrict__ wb = W + 128 * M_OUT;
#pragma unroll
        for (int k = 0; k < 6; ++k)
#pragma unroll
            for (int c = 0; c < M_OUT; ++c)
                acc[c] = fmaf(a[k], wb[k * M_OUT + c], acc[c]);
    }

    if (idx < cnt) {
        uint u[8];
#pragma unroll
        for (int i = 0; i < 8; ++i) {
            const float lo = fmaxf(acc[2 * i],     0.f);
            const float hi = fmaxf(acc[2 * i + 1], 0.f);
            u[i] = (uint)f2bf(lo) | ((uint)f2bf(hi) << 16);
        }
        uint4* orow = (uint4*)(featsb + (size_t)vid * 8);
        orow[0] = make_uint4(u[0], u[1], u[2], u[3]);
        orow[1] = make_uint4(u[4], u[5], u[6], u[7]);
    }
}

// ---------------------------------------------------------------------------
// K2: per-proposal segmented mean (bf16 gathers, f32 accumulate) + batchId +
// objectness. One block per contiguous segment; thread-per-point keeps 256
// independent idx->p2v->feats chains in flight; shfl+LDS reduction.
// out layout (f32): [P*16 means][P batchId][P ones]
// ---------------------------------------------------------------------------
__global__ __launch_bounds__(256) void k_propmean(
    const uint*  __restrict__ featsb,
    const int*   __restrict__ p2v,
    const int*   __restrict__ prop_idx,
    const int*   __restrict__ offsets,
    const int*   __restrict__ locs,
    float*       __restrict__ out)
{
    const int s   = blockIdx.x;
    const int tid = threadIdx.x;
    const int t0  = offsets[s];
    const int t1  = offsets[s + 1];

    float acc[M_OUT];
#pragma unroll
    for (int c = 0; c < M_OUT; ++c) acc[c] = 0.f;

    for (int t = t0 + tid; t < t1; t += 256) {
        const int p = prop_idx[2 * t + 1];
        const int v = p2v[p];
        const uint4* fp = (const uint4*)(featsb + (size_t)v * 8);
        const uint4 q0 = fp[0], q1 = fp[1];
        const uint u[8] = {q0.x, q0.y, q0.z, q0.w, q1.x, q1.y, q1.z, q1.w};
#pragma unroll
        for (int i = 0; i < 8; ++i) {
            acc[2 * i]     += __uint_as_float(u[i] << 16);
            acc[2 * i + 1] += __uint_as_float(u[i] & 0xFFFF0000u);
        }
    }

#pragma unroll
    for (int c = 0; c < M_OUT; ++c) {
#pragma unroll
        for (int off = 32; off > 0; off >>= 1)
            acc[c] += __shfl_down(acc[c], off, 64);
    }

    __shared__ float red[4][M_OUT];
    const int lane = tid & 63, wv = tid >> 6;
    if (lane == 0) {
#pragma unroll
        for (int c = 0; c < M_OUT; ++c) red[wv][c] = acc[c];
    }
    __syncthreads();

    if (tid < M_OUT) {
        const float sum = red[0][tid] + red[1][tid] + red[2][tid] + red[3][tid];
        const float cnt = (float)(t1 - t0);
        out[s * M_OUT + tid] = sum / fmaxf(cnt, 1.f);
    }
    if (tid == 0) {
        const int p = prop_idx[2 * t0 + 1];
        out[NUM_PROPOSALS * M_OUT + s]                 = (float)locs[4 * p];
        out[NUM_PROPOSALS * M_OUT + NUM_PROPOSALS + s] = 1.0f;
    }
}

// ---------------------------------------------------------------------------
extern "C" void kernel_launch(void* const* d_in, const int* in_sizes, int n_in,
                              void* d_out, int out_size, void* d_ws, size_t ws_size,
                              hipStream_t stream)
{
    const float* A    = (const float*)d_in[0];   // voxel_feats [1M][134]
    const float* W    = (const float*)d_in[1];   // [134][16]
    const int*   p2v  = (const int*)  d_in[2];   // [1.5M]
    const int*   pidx = (const int*)  d_in[3];   // [1M][2]
    const int*   offs = (const int*)  d_in[4];   // [2049]
    const int*   locs = (const int*)  d_in[5];   // [1.5M][4]
    float*       out  = (float*)      d_out;     // 36864 f32

    // ws layout: [0,32MB) bf16 feats; [32MB,33MB) flags; [33MB,+4B) count;
    //            [33MB+1KB, +4MB) compact ids
    char* ws = (char*)d_ws;
    uint*          featsb = (uint*)ws;
    unsigned char* flags  = (unsigned char*)(ws + (size_t)32 * 1024 * 1024);
    int*           count  = (int*)(ws + (size_t)33 * 1024 * 1024);
    int*           ids    = (int*)(ws + (size_t)33 * 1024 * 1024 + 1024);

    k_zero     <<<(NUM_VOXELS / 4 + 255) / 256, 256, 0, stream>>>((uint*)flags, count);
    k_set_flags<<<(TOTAL_PROP_PTS + 255) / 256, 256, 0, stream>>>(pidx, p2v, flags);
    k_compact  <<<(NUM_VOXELS + 255) / 256, 256, 0, stream>>>(flags, ids, count);
    k_gemm_relu<<<(NUM_VOXELS + 255) / 256, 256, 0, stream>>>(A, W, ids, count, featsb);
    k_propmean <<<NUM_PROPOSALS, 256, 0, stream>>>(featsb, p2v, pidx, offs, locs, out);
}